// Round 1
// 463.610 us; speedup vs baseline: 1.0005x; 1.0005x over previous
//
#include <hip/hip_runtime.h>
#include <hip/hip_bf16.h>

// channel_Encoding_Block — f32, packed v_pk_fma_f32 core, 4 blocks/CU.
//
//  x[b,c,t,d,i] (i fastest). emb[b,c,i,t,j] = sum_d x[b,c,t,d,i]*pos[c,j,d].
//  out[b,c,t,j,i] = sig(ys_c[b,i,t]) * sig(ln_y[b,c,i,t,j]) * x[b,c,t,j,i].
//
//  Algebraic fold: qkv = E @ W^T = x @ Wc^T with Wc = W @ pos^T  (wc_kernel,
//  6 blocks, once). Score scale C=0.5*log2e folded into Wc q-rows; log2e
//  folded into g,b. E stays in REGISTERS (residual only) -> E+qkv share one
//  barrier region: 3 syncs/block instead of 4, esw E-traffic gone.
//
//  Phase1: 768 blocks (b,c) -> sig(ys) gates (bf16) into d_ws.
//  Phase2: 24576 blocks (b,c,i), XCD-swizzled.
//
// Thread maps:  E/proj/LN: 2x2 tile (te=2*(tid>>4), je=2*(tid&15)); LN via
//               shfl_xor within 16-lane groups.
//               qkv: 4 tokens (tg=4*(tid>>5)) x 3 rows (rg=tid&31, f=rg+32m)
//               attn: (h=tid>>5, tt=tid&31)

using bf16 = __hip_bfloat16;
typedef float v2f __attribute__((ext_vector_type(2)));

__device__ __forceinline__ v2f pk_fma(v2f acc, v2f a, v2f b) {
  asm("v_pk_fma_f32 %0, %1, %2, %0" : "+v"(acc) : "v"(a), "v"(b));
  return acc;
}

struct __align__(16) SMem {
  float psJ[32][36];   // pos[j][d] (E stage); then aoF[t][f] (attn->proj)
  float wcF[96][34];   // Wc natural [f][d]  (q-rows pre-scaled by C)
  float w0s[32][36];   // w0[j][f], loaded at table time (stride 36: all rows 16B-aligned)
  float xs[32][36];    // x[t][d]; col32 = gate; col33/34 = g*log2e / b*log2e
  float qS[32][34];    // q[t][h*4+dh]
  float kT[32][36];    // k[h*4+dh][s]
  float vT[32][36];    // v[h*4+dh][s]
};                     // 40448 B -> 4 blocks/CU

// ---------------------------------------------------------------- wc kernel
__global__ __launch_bounds__(256) void wc_kernel(
    const float* __restrict__ pos_y, const float* __restrict__ wqvk_y,
    const float* __restrict__ wqvk_x, float* __restrict__ wc)
{
  const int n = blockIdx.x;          // 0..5:  n<3 -> y-set (c=n), n>=3 -> x-set
  const int c = n % 3, xset = n / 3;
  const float* W = (xset ? wqvk_x : wqvk_y) + c * 3072;   // [96][32]
  const float* P = pos_y + (xset ? 2 : c) * 1024;         // [32][32]
  __shared__ float Ws[96][33];
  __shared__ float Ps[32][33];
  const int tid = threadIdx.x;
#pragma unroll
  for (int k = 0; k < 12; ++k) {
    const int e = tid * 12 + k;
    Ws[e >> 5][e & 31] = W[e];
  }
#pragma unroll
  for (int k = 0; k < 4; ++k) {
    const int e = tid * 4 + k;
    Ps[e >> 5][e & 31] = P[e];
  }
  __syncthreads();
  const int fg = tid >> 3, d0 = (tid & 7) * 4;
#pragma unroll
  for (int m = 0; m < 3; ++m) {
    const int f = fg + 32 * m;
    float s0 = 0.f, s1 = 0.f, s2 = 0.f, s3 = 0.f;
#pragma unroll
    for (int j = 0; j < 32; ++j) {
      const float w = Ws[f][j];
      s0 += w * Ps[j][d0];     s1 += w * Ps[j][d0 + 1];
      s2 += w * Ps[j][d0 + 2]; s3 += w * Ps[j][d0 + 3];
    }
    // q-rows (f%24 in [0,8)) carry the score scale 0.5*log2(e)
    const float sc = ((f % 24) < 8) ? 0.72134752f : 1.0f;
    float* o = wc + (size_t)n * 3072 + f * 32 + d0;
    o[0] = s0 * sc; o[1] = s1 * sc; o[2] = s2 * sc; o[3] = s3 * sc;
  }
}

// -------------------------------------------------------------- table load
__device__ __forceinline__ void load_tables(
    SMem& sm, int tid, const float* __restrict__ xbc, int i,
    const float* __restrict__ pos, const float* __restrict__ wcg,
    const float* __restrict__ w0g,
    const float* __restrict__ g, const float* __restrict__ b)
{
  const int t = tid >> 3, dq = (tid & 7) * 4;
  // x slice: 4 strided scalars -> one float4 store (stride 36: aligned)
  float xv0 = xbc[(t * 32 + dq + 0) * 32 + i];
  float xv1 = xbc[(t * 32 + dq + 1) * 32 + i];
  float xv2 = xbc[(t * 32 + dq + 2) * 32 + i];
  float xv3 = xbc[(t * 32 + dq + 3) * 32 + i];
  *(float4*)&sm.xs[t][dq] = make_float4(xv0, xv1, xv2, xv3);
  // pos + w0 natural copies, float4
  {
    const int e = tid * 4;
    float4 p = *(const float4*)&pos[e];
    *(float4*)&sm.psJ[e >> 5][e & 31] = p;
    float4 w = *(const float4*)&w0g[e];
    *(float4*)&sm.w0s[e >> 5][e & 31] = w;
  }
  // Wc natural copy [f][d]: 3 float4 loads -> 6 v2f stores (rows stride 34)
  {
    float wf[12];
    *(float4*)&wf[0] = *(const float4*)&wcg[tid * 12];
    *(float4*)&wf[4] = *(const float4*)&wcg[tid * 12 + 4];
    *(float4*)&wf[8] = *(const float4*)&wcg[tid * 12 + 8];
#pragma unroll
    for (int k = 0; k < 6; ++k) {
      const int e = tid * 12 + 2 * k;
      *(v2f*)&sm.wcF[e >> 5][e & 31] = v2f{wf[2 * k], wf[2 * k + 1]};
    }
  }
  if (tid < 32) {
    sm.xs[tid][33] = g[tid] * 1.44269504f;   // g * log2(e)
    sm.xs[tid][34] = b[tid] * 1.44269504f;   // b * log2(e)
  }
}

// sigmoid(LayerNorm(E + MHSA(E))): thread's 2x2 outputs at rows te,te+1 /
// cols je,je+1.
__device__ __forceinline__ void mhsa_core(SMem& sm, int tid, float sig_out[2][2])
{
  const int te = (tid >> 4) * 2, je = (tid & 15) * 2;
  float eres[2][2];

  // ---- E (registers only) + qkv (x @ Wc^T), ONE barrier region ----
  {
    v2f a00{0.f,0.f}, a01{0.f,0.f}, a10{0.f,0.f}, a11{0.f,0.f};
#pragma unroll
    for (int d4 = 0; d4 < 8; ++d4) {
      float4 x0 = *(const float4*)&sm.xs[te][4 * d4];
      float4 x1 = *(const float4*)&sm.xs[te + 1][4 * d4];
      float4 p0 = *(const float4*)&sm.psJ[je][4 * d4];
      float4 p1 = *(const float4*)&sm.psJ[je + 1][4 * d4];
      a00 = pk_fma(a00, v2f{x0.x, x0.y}, v2f{p0.x, p0.y});
      a00 = pk_fma(a00, v2f{x0.z, x0.w}, v2f{p0.z, p0.w});
      a01 = pk_fma(a01, v2f{x0.x, x0.y}, v2f{p1.x, p1.y});
      a01 = pk_fma(a01, v2f{x0.z, x0.w}, v2f{p1.z, p1.w});
      a10 = pk_fma(a10, v2f{x1.x, x1.y}, v2f{p0.x, p0.y});
      a10 = pk_fma(a10, v2f{x1.z, x1.w}, v2f{p0.z, p0.w});
      a11 = pk_fma(a11, v2f{x1.x, x1.y}, v2f{p1.x, p1.y});
      a11 = pk_fma(a11, v2f{x1.z, x1.w}, v2f{p1.z, p1.w});
    }
    eres[0][0] = a00[0] + a00[1]; eres[0][1] = a01[0] + a01[1];
    eres[1][0] = a10[0] + a10[1]; eres[1][1] = a11[0] + a11[1];
  }
  {
    const int tg = (tid >> 5) * 4, rg = tid & 31;
    float* sp[3]; int st[3];
#pragma unroll
    for (int m = 0; m < 3; ++m) {
      const int f = rg + 32 * m;
      const int dh = f / 24, r2 = f - 24 * dh;
      const int sel = r2 >> 3, cc = (r2 & 7) * 4 + dh;
      if (sel == 0)      { sp[m] = &sm.qS[0][0] + cc;      st[m] = 34; }
      else if (sel == 1) { sp[m] = &sm.kT[0][0] + cc * 36; st[m] = 1;  }
      else               { sp[m] = &sm.vT[0][0] + cc * 36; st[m] = 1;  }
    }
    v2f acc[3][4];
#pragma unroll
    for (int m = 0; m < 3; ++m)
#pragma unroll
      for (int k = 0; k < 4; ++k) acc[m][k] = v2f{0.f, 0.f};
#pragma unroll
    for (int d4 = 0; d4 < 8; ++d4) {
      float4 a0 = *(const float4*)&sm.xs[tg + 0][4 * d4];
      float4 a1 = *(const float4*)&sm.xs[tg + 1][4 * d4];
      float4 a2 = *(const float4*)&sm.xs[tg + 2][4 * d4];
      float4 a3 = *(const float4*)&sm.xs[tg + 3][4 * d4];
#pragma unroll
      for (int m = 0; m < 3; ++m) {
        v2f wlo = *(const v2f*)&sm.wcF[rg + 32 * m][4 * d4];
        v2f whi = *(const v2f*)&sm.wcF[rg + 32 * m][4 * d4 + 2];
        acc[m][0] = pk_fma(acc[m][0], v2f{a0.x, a0.y}, wlo);
        acc[m][0] = pk_fma(acc[m][0], v2f{a0.z, a0.w}, whi);
        acc[m][1] = pk_fma(acc[m][1], v2f{a1.x, a1.y}, wlo);
        acc[m][1] = pk_fma(acc[m][1], v2f{a1.z, a1.w}, whi);
        acc[m][2] = pk_fma(acc[m][2], v2f{a2.x, a2.y}, wlo);
        acc[m][2] = pk_fma(acc[m][2], v2f{a2.z, a2.w}, whi);
        acc[m][3] = pk_fma(acc[m][3], v2f{a3.x, a3.y}, wlo);
        acc[m][3] = pk_fma(acc[m][3], v2f{a3.z, a3.w}, whi);
      }
    }
#pragma unroll
    for (int m = 0; m < 3; ++m)
#pragma unroll
      for (int k = 0; k < 4; ++k)
        sp[m][(tg + k) * st[m]] = acc[m][k][0] + acc[m][k][1];
  }
  __syncthreads();

  // ---- attention: (h, tt); q pre-scaled by C via Wc; no max-pass ----
  {
    const int h = tid >> 5, tt = tid & 31;
    v2f qa = *(const v2f*)&sm.qS[tt][4 * h];
    v2f qb = *(const v2f*)&sm.qS[tt][4 * h + 2];
    v2f q0 = v2f{qa[0], qa[0]}, q1 = v2f{qa[1], qa[1]};
    v2f q2 = v2f{qb[0], qb[0]}, q3 = v2f{qb[1], qb[1]};
    const float* kr0 = &sm.kT[4 * h + 0][0];
    const float* kr1 = &sm.kT[4 * h + 1][0];
    const float* kr2 = &sm.kT[4 * h + 2][0];
    const float* kr3 = &sm.kT[4 * h + 3][0];
    v2f sc2[16];
#pragma unroll
    for (int s4 = 0; s4 < 8; ++s4) {
      float4 k0 = *(const float4*)&kr0[4 * s4];
      float4 k1 = *(const float4*)&kr1[4 * s4];
      float4 k2 = *(const float4*)&kr2[4 * s4];
      float4 k3 = *(const float4*)&kr3[4 * s4];
      v2f ea = v2f{0.f, 0.f}, eb = v2f{0.f, 0.f};
      ea = pk_fma(ea, q0, v2f{k0.x, k0.y}); eb = pk_fma(eb, q0, v2f{k0.z, k0.w});
      ea = pk_fma(ea, q1, v2f{k1.x, k1.y}); eb = pk_fma(eb, q1, v2f{k1.z, k1.w});
      ea = pk_fma(ea, q2, v2f{k2.x, k2.y}); eb = pk_fma(eb, q2, v2f{k2.z, k2.w});
      ea = pk_fma(ea, q3, v2f{k3.x, k3.y}); eb = pk_fma(eb, q3, v2f{k3.z, k3.w});
      sc2[2 * s4] = ea; sc2[2 * s4 + 1] = eb;
    }
    v2f den = v2f{0.f, 0.f};
#pragma unroll
    for (int s2 = 0; s2 < 16; ++s2) {
      sc2[s2][0] = exp2f(sc2[s2][0]);
      sc2[s2][1] = exp2f(sc2[s2][1]);
      den += sc2[s2];
    }
    const float inv = __fdividef(1.0f, den[0] + den[1]);
    const float* vr0 = &sm.vT[4 * h + 0][0];
    const float* vr1 = &sm.vT[4 * h + 1][0];
    const float* vr2 = &sm.vT[4 * h + 2][0];
    const float* vr3 = &sm.vT[4 * h + 3][0];
    v2f o0 = v2f{0.f,0.f}, o1 = v2f{0.f,0.f}, o2 = v2f{0.f,0.f}, o3 = v2f{0.f,0.f};
#pragma unroll
    for (int s4 = 0; s4 < 8; ++s4) {
      v2f aa = sc2[2 * s4], ab = sc2[2 * s4 + 1];
      float4 v0 = *(const float4*)&vr0[4 * s4];
      float4 v1 = *(const float4*)&vr1[4 * s4];
      float4 v2v = *(const float4*)&vr2[4 * s4];
      float4 v3 = *(const float4*)&vr3[4 * s4];
      o0 = pk_fma(o0, aa, v2f{v0.x, v0.y});   o0 = pk_fma(o0, ab, v2f{v0.z, v0.w});
      o1 = pk_fma(o1, aa, v2f{v1.x, v1.y});   o1 = pk_fma(o1, ab, v2f{v1.z, v1.w});
      o2 = pk_fma(o2, aa, v2f{v2v.x, v2v.y}); o2 = pk_fma(o2, ab, v2f{v2v.z, v2v.w});
      o3 = pk_fma(o3, aa, v2f{v3.x, v3.y});   o3 = pk_fma(o3, ab, v2f{v3.z, v3.w});
    }
    float4 ao;
    ao.x = (o0[0] + o0[1]) * inv;  ao.y = (o1[0] + o1[1]) * inv;
    ao.z = (o2[0] + o2[1]) * inv;  ao.w = (o3[0] + o3[1]) * inv;
    *(float4*)&sm.psJ[tt][4 * h] = ao;           // aoF (psJ union, pos dead)
  }
  __syncthreads();

  // ---- proj + residual + LN + sigmoid (2x2 tile, all-float4 reads) ----
  {
    v2f a00{0.f,0.f}, a01{0.f,0.f}, a10{0.f,0.f}, a11{0.f,0.f};
#pragma unroll
    for (int f4 = 0; f4 < 8; ++f4) {
      float4 u0 = *(const float4*)&sm.psJ[te][4 * f4];       // aoF row te
      float4 u1 = *(const float4*)&sm.psJ[te + 1][4 * f4];
      float4 w0 = *(const float4*)&sm.w0s[je][4 * f4];       // w0[j][f]
      float4 w1 = *(const float4*)&sm.w0s[je + 1][4 * f4];
      a00 = pk_fma(a00, v2f{u0.x, u0.y}, v2f{w0.x, w0.y});
      a00 = pk_fma(a00, v2f{u0.z, u0.w}, v2f{w0.z, w0.w});
      a01 = pk_fma(a01, v2f{u0.x, u0.y}, v2f{w1.x, w1.y});
      a01 = pk_fma(a01, v2f{u0.z, u0.w}, v2f{w1.z, w1.w});
      a10 = pk_fma(a10, v2f{u1.x, u1.y}, v2f{w0.x, w0.y});
      a10 = pk_fma(a10, v2f{u1.z, u1.w}, v2f{w0.z, w0.w});
      a11 = pk_fma(a11, v2f{u1.x, u1.y}, v2f{w1.x, w1.y});
      a11 = pk_fma(a11, v2f{u1.z, u1.w}, v2f{w1.z, w1.w});
    }
    float rr[2][2];
    rr[0][0] = a00[0] + a00[1] + eres[0][0];
    rr[0][1] = a01[0] + a01[1] + eres[0][1];
    rr[1][0] = a10[0] + a10[1] + eres[1][0];
    rr[1][1] = a11[0] + a11[1] + eres[1][1];
    float s1a = rr[0][0] + rr[0][1], s1b = rr[1][0] + rr[1][1];
    float s2a = rr[0][0]*rr[0][0] + rr[0][1]*rr[0][1];
    float s2b = rr[1][0]*rr[1][0] + rr[1][1]*rr[1][1];
#pragma unroll
    for (int m = 1; m < 16; m <<= 1) {      // reduce within 16-lane group (same te)
      s1a += __shfl_xor(s1a, m, 64);
      s2a += __shfl_xor(s2a, m, 64);
      s1b += __shfl_xor(s1b, m, 64);
      s2b += __shfl_xor(s2b, m, 64);
    }
    const float mua = s1a * (1.0f / 32.0f), mub = s1b * (1.0f / 32.0f);
    const float ra = rsqrtf(s2a * (1.0f / 32.0f) - mua * mua + 1e-5f);
    const float rb = rsqrtf(s2b * (1.0f / 32.0f) - mub * mub + 1e-5f);
    const float g0 = sm.xs[je][33],     b0 = sm.xs[je][34];       // pre-scaled by log2e
    const float g1 = sm.xs[je + 1][33], b1 = sm.xs[je + 1][34];
    sig_out[0][0] = __fdividef(1.0f, 1.0f + exp2f(-((rr[0][0] - mua) * ra * g0 + b0)));
    sig_out[0][1] = __fdividef(1.0f, 1.0f + exp2f(-((rr[0][1] - mua) * ra * g1 + b1)));
    sig_out[1][0] = __fdividef(1.0f, 1.0f + exp2f(-((rr[1][0] - mub) * rb * g0 + b0)));
    sig_out[1][1] = __fdividef(1.0f, 1.0f + exp2f(-((rr[1][1] - mub) * rb * g1 + b1)));
  }
}

__global__ __launch_bounds__(256, 4) void phase1_kernel(
    const float* __restrict__ x, const float* __restrict__ pos_y,
    const float* __restrict__ wc, const float* __restrict__ w0_x,
    const float* __restrict__ g_x, const float* __restrict__ b_x,
    bf16* __restrict__ gates)
{
  __shared__ SMem sm;
  const int tid = threadIdx.x;
  const int n = blockIdx.x;          // 768 = 256*3
  const int c = n % 3, b = n / 3;
  const float* xbc = x + (size_t)(b * 3 + 2) * 32768;   // channel 2
  load_tables(sm, tid, xbc, 31, pos_y + 2 * 1024,
              wc + (size_t)(3 + c) * 3072, w0_x + c * 1024, g_x, b_x);
  __syncthreads();
  float sig[2][2];
  mhsa_core(sm, tid, sig);
  const int te = (tid >> 4) * 2, je = (tid & 15) * 2;
#pragma unroll
  for (int u = 0; u < 2; ++u)
#pragma unroll
    for (int v = 0; v < 2; ++v)
      gates[((c * 256 + b) * 32 + te + u) * 32 + je + v] = __float2bfloat16(sig[u][v]);
}

__global__ __launch_bounds__(256, 4) void phase2_kernel(
    const float* __restrict__ x, const float* __restrict__ pos_y,
    const float* __restrict__ wc, const float* __restrict__ w0_y,
    const float* __restrict__ g_y, const float* __restrict__ b_y,
    const bf16* __restrict__ gates, float* __restrict__ out)
{
  __shared__ SMem sm;
  const int tid = threadIdx.x;
  const int n = blockIdx.x;                    // 24576
  const int p = (n & 7) * 3072 + (n >> 3);     // XCD swizzle
  const int i = p & 31, bc = p >> 5;
  const int c = bc % 3, b = bc / 3;
  const float* xbc = x + (size_t)bc * 32768;
  load_tables(sm, tid, xbc, i, pos_y + c * 1024,
              wc + (size_t)c * 3072, w0_y + c * 1024, g_y, b_y);
  if (tid < 32)
    sm.xs[tid][32] = __bfloat162float(gates[((c * 256 + b) * 32 + i) * 32 + tid]);
  __syncthreads();
  float sig[2][2];
  mhsa_core(sm, tid, sig);
  const int te = (tid >> 4) * 2, je = (tid & 15) * 2;
  float* ob = out + (size_t)bc * 32768 + i;
#pragma unroll
  for (int u = 0; u < 2; ++u) {
    const float sgv = sm.xs[te + u][32];       // sig(ys_c[b, i, t])
#pragma unroll
    for (int v = 0; v < 2; ++v)
      ob[((te + u) * 32 + je + v) * 32] = sgv * sig[u][v] * sm.xs[te + u][je + v];
  }
}

extern "C" void kernel_launch(void* const* d_in, const int* in_sizes, int n_in,
                              void* d_out, int out_size, void* d_ws, size_t ws_size,
                              hipStream_t stream) {
  const float* x      = (const float*)d_in[0];
  const float* pos_y  = (const float*)d_in[1];
  const float* wqvk_y = (const float*)d_in[2];
  const float* w0_y   = (const float*)d_in[3];
  const float* g_y    = (const float*)d_in[4];
  const float* b_y    = (const float*)d_in[5];
  const float* wqvk_x = (const float*)d_in[6];
  const float* w0_x   = (const float*)d_in[7];
  const float* g_x    = (const float*)d_in[8];
  const float* b_x    = (const float*)d_in[9];
  bf16*  gates = (bf16*)d_ws;                              // 1.5 MB
  float* wcbuf = (float*)((char*)d_ws + 1572864);          // 6*96*32 f32 = 72 KB

  hipLaunchKernelGGL(wc_kernel, dim3(6), dim3(256), 0, stream,
                     pos_y, wqvk_y, wqvk_x, wcbuf);
  hipLaunchKernelGGL(phase1_kernel, dim3(768), dim3(256), 0, stream,
                     x, pos_y, wcbuf, w0_x, g_x, b_x, gates);
  hipLaunchKernelGGL(phase2_kernel, dim3(24576), dim3(256), 0, stream,
                     x, pos_y, wcbuf, w0_y, g_y, b_y, gates, (float*)d_out);
}

// Round 2
// 451.663 us; speedup vs baseline: 1.0270x; 1.0265x over previous
//
#include <hip/hip_runtime.h>
#include <hip/hip_bf16.h>

// channel_Encoding_Block — f32, packed v_pk_fma_f32 core, 4 blocks/CU.
//
//  x[b,c,t,d,i] (i fastest). emb[b,c,i,t,j] = sum_d x[b,c,t,d,i]*pos[c,j,d].
//  out[b,c,t,j,i] = sig(ys_c[b,i,t]) * sig(ln_y[b,c,i,t,j]) * x[b,c,t,j,i].
//
//  Algebraic fold: qkv = E @ W^T = x @ Wc^T with Wc = W @ pos^T  (wc_kernel,
//  6 blocks, once). Score scale C=0.5*log2e folded into Wc q-rows; log2e
//  folded into g,b. E stays in REGISTERS (residual only) -> 3 syncs/block.
//
//  Phase1: 768 blocks (b,c) -> sig(ys) gates (bf16) into d_ws.
//  Phase2: 24576 blocks (b,c,i), XCD-swizzled.
//
// Thread maps:  E/proj/LN: 2x2 tile rows {g,g+16} cols {l,l+16}
//               (g=tid>>4, l=tid&15)  — column reads hit rows 0..15 =
//               2-way bank aliasing (free); row reads broadcast.  [R2 fix:
//               the je=2*(tid&15) mapping was a 4-way conflict]
//               qkv: 4 tokens (tg=4*(tid>>5)) x 3 rows (rg=tid&31, f=rg+32m);
//               k/v scatter stores vectorized to ds_write_b128 (token-contig).
//               attn: (h=tid>>5, tt=tid&31); k/v reads wave-broadcast.

using bf16 = __hip_bfloat16;
typedef float v2f __attribute__((ext_vector_type(2)));

__device__ __forceinline__ v2f pk_fma(v2f acc, v2f a, v2f b) {
  asm("v_pk_fma_f32 %0, %1, %2, %0" : "+v"(acc) : "v"(a), "v"(b));
  return acc;
}

struct __align__(16) SMem {
  float psJ[32][36];   // pos[j][d] (E stage); then aoF[t][f] (attn->proj)
  float wcF[96][34];   // Wc natural [f][d]  (q-rows pre-scaled by C)
  float w0s[32][36];   // w0[j][f]
  float xs[32][36];    // x[t][d]; col32 = gate; col33/34 = g*log2e / b*log2e
  float qS[32][34];    // q[t][h*4+dh]
  float kT[32][36];    // k[h*4+dh][s]
  float vT[32][36];    // v[h*4+dh][s]
};                     // 40448 B -> 4 blocks/CU

// ---------------------------------------------------------------- wc kernel
__global__ __launch_bounds__(256) void wc_kernel(
    const float* __restrict__ pos_y, const float* __restrict__ wqvk_y,
    const float* __restrict__ wqvk_x, float* __restrict__ wc)
{
  const int n = blockIdx.x;          // 0..5:  n<3 -> y-set (c=n), n>=3 -> x-set
  const int c = n % 3, xset = n / 3;
  const float* W = (xset ? wqvk_x : wqvk_y) + c * 3072;   // [96][32]
  const float* P = pos_y + (xset ? 2 : c) * 1024;         // [32][32]
  __shared__ float Ws[96][33];
  __shared__ float Ps[32][33];
  const int tid = threadIdx.x;
#pragma unroll
  for (int k = 0; k < 12; ++k) {
    const int e = tid * 12 + k;
    Ws[e >> 5][e & 31] = W[e];
  }
#pragma unroll
  for (int k = 0; k < 4; ++k) {
    const int e = tid * 4 + k;
    Ps[e >> 5][e & 31] = P[e];
  }
  __syncthreads();
  const int fg = tid >> 3, d0 = (tid & 7) * 4;
#pragma unroll
  for (int m = 0; m < 3; ++m) {
    const int f = fg + 32 * m;
    float s0 = 0.f, s1 = 0.f, s2 = 0.f, s3 = 0.f;
#pragma unroll
    for (int j = 0; j < 32; ++j) {
      const float w = Ws[f][j];
      s0 += w * Ps[j][d0];     s1 += w * Ps[j][d0 + 1];
      s2 += w * Ps[j][d0 + 2]; s3 += w * Ps[j][d0 + 3];
    }
    // q-rows (f%24 in [0,8)) carry the score scale 0.5*log2(e)
    const float sc = ((f % 24) < 8) ? 0.72134752f : 1.0f;
    float* o = wc + (size_t)n * 3072 + f * 32 + d0;
    o[0] = s0 * sc; o[1] = s1 * sc; o[2] = s2 * sc; o[3] = s3 * sc;
  }
}

// -------------------------------------------------------------- table load
__device__ __forceinline__ void load_tables(
    SMem& sm, int tid, const float* __restrict__ xbc, int i,
    const float* __restrict__ pos, const float* __restrict__ wcg,
    const float* __restrict__ w0g,
    const float* __restrict__ g, const float* __restrict__ b)
{
  const int t = tid >> 3, dq = (tid & 7) * 4;
  // x slice: 4 strided scalars -> one float4 store (stride 36: aligned)
  float xv0 = xbc[(t * 32 + dq + 0) * 32 + i];
  float xv1 = xbc[(t * 32 + dq + 1) * 32 + i];
  float xv2 = xbc[(t * 32 + dq + 2) * 32 + i];
  float xv3 = xbc[(t * 32 + dq + 3) * 32 + i];
  *(float4*)&sm.xs[t][dq] = make_float4(xv0, xv1, xv2, xv3);
  // pos + w0 natural copies, float4
  {
    const int e = tid * 4;
    float4 p = *(const float4*)&pos[e];
    *(float4*)&sm.psJ[e >> 5][e & 31] = p;
    float4 w = *(const float4*)&w0g[e];
    *(float4*)&sm.w0s[e >> 5][e & 31] = w;
  }
  // Wc natural copy [f][d]: 3 float4 loads -> 6 v2f stores (rows stride 34)
  {
    float wf[12];
    *(float4*)&wf[0] = *(const float4*)&wcg[tid * 12];
    *(float4*)&wf[4] = *(const float4*)&wcg[tid * 12 + 4];
    *(float4*)&wf[8] = *(const float4*)&wcg[tid * 12 + 8];
#pragma unroll
    for (int k = 0; k < 6; ++k) {
      const int e = tid * 12 + 2 * k;
      *(v2f*)&sm.wcF[e >> 5][e & 31] = v2f{wf[2 * k], wf[2 * k + 1]};
    }
  }
  if (tid < 32) {
    sm.xs[tid][33] = g[tid] * 1.44269504f;   // g * log2(e)
    sm.xs[tid][34] = b[tid] * 1.44269504f;   // b * log2(e)
  }
}

// sigmoid(LayerNorm(E + MHSA(E))): thread's 2x2 outputs at rows {g,g+16},
// cols {l,l+16}.
__device__ __forceinline__ void mhsa_core(SMem& sm, int tid, float sig_out[2][2])
{
  const int g = tid >> 4, l = tid & 15;
  float eres[2][2];

  // ---- E (registers only) + qkv (x @ Wc^T), ONE barrier region ----
  {
    v2f a00{0.f,0.f}, a01{0.f,0.f}, a10{0.f,0.f}, a11{0.f,0.f};
#pragma unroll
    for (int d4 = 0; d4 < 8; ++d4) {
      float4 x0 = *(const float4*)&sm.xs[g][4 * d4];        // broadcast
      float4 x1 = *(const float4*)&sm.xs[g + 16][4 * d4];   // broadcast
      float4 p0 = *(const float4*)&sm.psJ[l][4 * d4];       // 2-way (free)
      float4 p1 = *(const float4*)&sm.psJ[l + 16][4 * d4];
      a00 = pk_fma(a00, v2f{x0.x, x0.y}, v2f{p0.x, p0.y});
      a00 = pk_fma(a00, v2f{x0.z, x0.w}, v2f{p0.z, p0.w});
      a01 = pk_fma(a01, v2f{x0.x, x0.y}, v2f{p1.x, p1.y});
      a01 = pk_fma(a01, v2f{x0.z, x0.w}, v2f{p1.z, p1.w});
      a10 = pk_fma(a10, v2f{x1.x, x1.y}, v2f{p0.x, p0.y});
      a10 = pk_fma(a10, v2f{x1.z, x1.w}, v2f{p0.z, p0.w});
      a11 = pk_fma(a11, v2f{x1.x, x1.y}, v2f{p1.x, p1.y});
      a11 = pk_fma(a11, v2f{x1.z, x1.w}, v2f{p1.z, p1.w});
    }
    eres[0][0] = a00[0] + a00[1]; eres[0][1] = a01[0] + a01[1];
    eres[1][0] = a10[0] + a10[1]; eres[1][1] = a11[0] + a11[1];
  }
  {
    const int tg = (tid >> 5) * 4, rg = tid & 31;
    float* sp[3]; int st[3];
#pragma unroll
    for (int m = 0; m < 3; ++m) {
      const int f = rg + 32 * m;
      const int dh = f / 24, r2 = f - 24 * dh;
      const int sel = r2 >> 3, cc = (r2 & 7) * 4 + dh;
      if (sel == 0)      { sp[m] = &sm.qS[0][0] + cc;      st[m] = 34; }
      else if (sel == 1) { sp[m] = &sm.kT[0][0] + cc * 36; st[m] = 1;  }
      else               { sp[m] = &sm.vT[0][0] + cc * 36; st[m] = 1;  }
    }
    v2f acc[3][4];
#pragma unroll
    for (int m = 0; m < 3; ++m)
#pragma unroll
      for (int k = 0; k < 4; ++k) acc[m][k] = v2f{0.f, 0.f};
#pragma unroll
    for (int d4 = 0; d4 < 8; ++d4) {
      float4 a0 = *(const float4*)&sm.xs[tg + 0][4 * d4];   // broadcast
      float4 a1 = *(const float4*)&sm.xs[tg + 1][4 * d4];
      float4 a2 = *(const float4*)&sm.xs[tg + 2][4 * d4];
      float4 a3 = *(const float4*)&sm.xs[tg + 3][4 * d4];
#pragma unroll
      for (int m = 0; m < 3; ++m) {
        v2f wlo = *(const v2f*)&sm.wcF[rg + 32 * m][4 * d4];      // 2-way (free)
        v2f whi = *(const v2f*)&sm.wcF[rg + 32 * m][4 * d4 + 2];
        acc[m][0] = pk_fma(acc[m][0], v2f{a0.x, a0.y}, wlo);
        acc[m][0] = pk_fma(acc[m][0], v2f{a0.z, a0.w}, whi);
        acc[m][1] = pk_fma(acc[m][1], v2f{a1.x, a1.y}, wlo);
        acc[m][1] = pk_fma(acc[m][1], v2f{a1.z, a1.w}, whi);
        acc[m][2] = pk_fma(acc[m][2], v2f{a2.x, a2.y}, wlo);
        acc[m][2] = pk_fma(acc[m][2], v2f{a2.z, a2.w}, whi);
        acc[m][3] = pk_fma(acc[m][3], v2f{a3.x, a3.y}, wlo);
        acc[m][3] = pk_fma(acc[m][3], v2f{a3.z, a3.w}, whi);
      }
    }
#pragma unroll
    for (int m = 0; m < 3; ++m) {
      const float r0 = acc[m][0][0] + acc[m][0][1];
      const float r1 = acc[m][1][0] + acc[m][1][1];
      const float r2v = acc[m][2][0] + acc[m][2][1];
      const float r3 = acc[m][3][0] + acc[m][3][1];
      if (st[m] == 1) {
        // k/v rows: token-contiguous, 16B-aligned (tg%4==0) -> one b128 store
        *(float4*)(sp[m] + tg) = make_float4(r0, r1, r2v, r3);
      } else {
        // q rows: strided scatter (4 scalars)
        sp[m][(tg + 0) * 34] = r0;
        sp[m][(tg + 1) * 34] = r1;
        sp[m][(tg + 2) * 34] = r2v;
        sp[m][(tg + 3) * 34] = r3;
      }
    }
  }
  __syncthreads();

  // ---- attention: (h, tt); q pre-scaled by C via Wc; no max-pass ----
  {
    const int h = tid >> 5, tt = tid & 31;
    v2f qa = *(const v2f*)&sm.qS[tt][4 * h];
    v2f qb = *(const v2f*)&sm.qS[tt][4 * h + 2];
    v2f q0 = v2f{qa[0], qa[0]}, q1 = v2f{qa[1], qa[1]};
    v2f q2 = v2f{qb[0], qb[0]}, q3 = v2f{qb[1], qb[1]};
    const float* kr0 = &sm.kT[4 * h + 0][0];
    const float* kr1 = &sm.kT[4 * h + 1][0];
    const float* kr2 = &sm.kT[4 * h + 2][0];
    const float* kr3 = &sm.kT[4 * h + 3][0];
    v2f sc2[16];
#pragma unroll
    for (int s4 = 0; s4 < 8; ++s4) {
      float4 k0 = *(const float4*)&kr0[4 * s4];
      float4 k1 = *(const float4*)&kr1[4 * s4];
      float4 k2 = *(const float4*)&kr2[4 * s4];
      float4 k3 = *(const float4*)&kr3[4 * s4];
      v2f ea = v2f{0.f, 0.f}, eb = v2f{0.f, 0.f};
      ea = pk_fma(ea, q0, v2f{k0.x, k0.y}); eb = pk_fma(eb, q0, v2f{k0.z, k0.w});
      ea = pk_fma(ea, q1, v2f{k1.x, k1.y}); eb = pk_fma(eb, q1, v2f{k1.z, k1.w});
      ea = pk_fma(ea, q2, v2f{k2.x, k2.y}); eb = pk_fma(eb, q2, v2f{k2.z, k2.w});
      ea = pk_fma(ea, q3, v2f{k3.x, k3.y}); eb = pk_fma(eb, q3, v2f{k3.z, k3.w});
      sc2[2 * s4] = ea; sc2[2 * s4 + 1] = eb;
    }
    v2f den = v2f{0.f, 0.f};
#pragma unroll
    for (int s2 = 0; s2 < 16; ++s2) {
      sc2[s2][0] = exp2f(sc2[s2][0]);
      sc2[s2][1] = exp2f(sc2[s2][1]);
      den += sc2[s2];
    }
    const float inv = __fdividef(1.0f, den[0] + den[1]);
    const float* vr0 = &sm.vT[4 * h + 0][0];
    const float* vr1 = &sm.vT[4 * h + 1][0];
    const float* vr2 = &sm.vT[4 * h + 2][0];
    const float* vr3 = &sm.vT[4 * h + 3][0];
    v2f o0 = v2f{0.f,0.f}, o1 = v2f{0.f,0.f}, o2 = v2f{0.f,0.f}, o3 = v2f{0.f,0.f};
#pragma unroll
    for (int s4 = 0; s4 < 8; ++s4) {
      v2f aa = sc2[2 * s4], ab = sc2[2 * s4 + 1];
      float4 v0 = *(const float4*)&vr0[4 * s4];
      float4 v1 = *(const float4*)&vr1[4 * s4];
      float4 v2v = *(const float4*)&vr2[4 * s4];
      float4 v3 = *(const float4*)&vr3[4 * s4];
      o0 = pk_fma(o0, aa, v2f{v0.x, v0.y});   o0 = pk_fma(o0, ab, v2f{v0.z, v0.w});
      o1 = pk_fma(o1, aa, v2f{v1.x, v1.y});   o1 = pk_fma(o1, ab, v2f{v1.z, v1.w});
      o2 = pk_fma(o2, aa, v2f{v2v.x, v2v.y}); o2 = pk_fma(o2, ab, v2f{v2v.z, v2v.w});
      o3 = pk_fma(o3, aa, v2f{v3.x, v3.y});   o3 = pk_fma(o3, ab, v2f{v3.z, v3.w});
    }
    float4 ao;
    ao.x = (o0[0] + o0[1]) * inv;  ao.y = (o1[0] + o1[1]) * inv;
    ao.z = (o2[0] + o2[1]) * inv;  ao.w = (o3[0] + o3[1]) * inv;
    *(float4*)&sm.psJ[tt][4 * h] = ao;           // aoF (psJ union, pos dead)
  }
  __syncthreads();

  // ---- proj + residual + LN + sigmoid (2x2 tile, conflict-free) ----
  {
    v2f a00{0.f,0.f}, a01{0.f,0.f}, a10{0.f,0.f}, a11{0.f,0.f};
#pragma unroll
    for (int f4 = 0; f4 < 8; ++f4) {
      float4 u0 = *(const float4*)&sm.psJ[g][4 * f4];        // aoF, broadcast
      float4 u1 = *(const float4*)&sm.psJ[g + 16][4 * f4];
      float4 w0 = *(const float4*)&sm.w0s[l][4 * f4];        // 2-way (free)
      float4 w1 = *(const float4*)&sm.w0s[l + 16][4 * f4];
      a00 = pk_fma(a00, v2f{u0.x, u0.y}, v2f{w0.x, w0.y});
      a00 = pk_fma(a00, v2f{u0.z, u0.w}, v2f{w0.z, w0.w});
      a01 = pk_fma(a01, v2f{u0.x, u0.y}, v2f{w1.x, w1.y});
      a01 = pk_fma(a01, v2f{u0.z, u0.w}, v2f{w1.z, w1.w});
      a10 = pk_fma(a10, v2f{u1.x, u1.y}, v2f{w0.x, w0.y});
      a10 = pk_fma(a10, v2f{u1.z, u1.w}, v2f{w0.z, w0.w});
      a11 = pk_fma(a11, v2f{u1.x, u1.y}, v2f{w1.x, w1.y});
      a11 = pk_fma(a11, v2f{u1.z, u1.w}, v2f{w1.z, w1.w});
    }
    float rr[2][2];
    rr[0][0] = a00[0] + a00[1] + eres[0][0];
    rr[0][1] = a01[0] + a01[1] + eres[0][1];
    rr[1][0] = a10[0] + a10[1] + eres[1][0];
    rr[1][1] = a11[0] + a11[1] + eres[1][1];
    float s1a = rr[0][0] + rr[0][1], s1b = rr[1][0] + rr[1][1];
    float s2a = rr[0][0]*rr[0][0] + rr[0][1]*rr[0][1];
    float s2b = rr[1][0]*rr[1][0] + rr[1][1]*rr[1][1];
#pragma unroll
    for (int m = 1; m < 16; m <<= 1) {      // reduce within 16-lane group (same g)
      s1a += __shfl_xor(s1a, m, 64);
      s2a += __shfl_xor(s2a, m, 64);
      s1b += __shfl_xor(s1b, m, 64);
      s2b += __shfl_xor(s2b, m, 64);
    }
    const float mua = s1a * (1.0f / 32.0f), mub = s1b * (1.0f / 32.0f);
    const float ra = rsqrtf(s2a * (1.0f / 32.0f) - mua * mua + 1e-5f);
    const float rb = rsqrtf(s2b * (1.0f / 32.0f) - mub * mub + 1e-5f);
    const float g0 = sm.xs[l][33],      b0 = sm.xs[l][34];       // pre-scaled by log2e
    const float g1 = sm.xs[l + 16][33], b1 = sm.xs[l + 16][34];
    sig_out[0][0] = __fdividef(1.0f, 1.0f + exp2f(-((rr[0][0] - mua) * ra * g0 + b0)));
    sig_out[0][1] = __fdividef(1.0f, 1.0f + exp2f(-((rr[0][1] - mua) * ra * g1 + b1)));
    sig_out[1][0] = __fdividef(1.0f, 1.0f + exp2f(-((rr[1][0] - mub) * rb * g0 + b0)));
    sig_out[1][1] = __fdividef(1.0f, 1.0f + exp2f(-((rr[1][1] - mub) * rb * g1 + b1)));
  }
}

__global__ __launch_bounds__(256, 4) void phase1_kernel(
    const float* __restrict__ x, const float* __restrict__ pos_y,
    const float* __restrict__ wc, const float* __restrict__ w0_x,
    const float* __restrict__ g_x, const float* __restrict__ b_x,
    bf16* __restrict__ gates)
{
  __shared__ SMem sm;
  const int tid = threadIdx.x;
  const int n = blockIdx.x;          // 768 = 256*3
  const int c = n % 3, b = n / 3;
  const float* xbc = x + (size_t)(b * 3 + 2) * 32768;   // channel 2
  load_tables(sm, tid, xbc, 31, pos_y + 2 * 1024,
              wc + (size_t)(3 + c) * 3072, w0_x + c * 1024, g_x, b_x);
  __syncthreads();
  float sig[2][2];
  mhsa_core(sm, tid, sig);
  const int g = tid >> 4, l = tid & 15;
#pragma unroll
  for (int u = 0; u < 2; ++u)
#pragma unroll
    for (int v = 0; v < 2; ++v)
      gates[((c * 256 + b) * 32 + g + 16 * u) * 32 + l + 16 * v] =
          __float2bfloat16(sig[u][v]);
}

__global__ __launch_bounds__(256, 4) void phase2_kernel(
    const float* __restrict__ x, const float* __restrict__ pos_y,
    const float* __restrict__ wc, const float* __restrict__ w0_y,
    const float* __restrict__ g_y, const float* __restrict__ b_y,
    const bf16* __restrict__ gates, float* __restrict__ out)
{
  __shared__ SMem sm;
  const int tid = threadIdx.x;
  const int n = blockIdx.x;                    // 24576
  const int p = (n & 7) * 3072 + (n >> 3);     // XCD swizzle
  const int i = p & 31, bc = p >> 5;
  const int c = bc % 3, b = bc / 3;
  const float* xbc = x + (size_t)bc * 32768;
  load_tables(sm, tid, xbc, i, pos_y + c * 1024,
              wc + (size_t)c * 3072, w0_y + c * 1024, g_y, b_y);
  if (tid < 32)
    sm.xs[tid][32] = __bfloat162float(gates[((c * 256 + b) * 32 + i) * 32 + tid]);
  __syncthreads();
  float sig[2][2];
  mhsa_core(sm, tid, sig);
  const int g = tid >> 4, l = tid & 15;
  float* ob = out + (size_t)bc * 32768 + i;
#pragma unroll
  for (int u = 0; u < 2; ++u) {
    const int r = g + 16 * u;
    const float sgv = sm.xs[r][32];            // sig(ys_c[b, i, t])
#pragma unroll
    for (int v = 0; v < 2; ++v) {
      const int cc = l + 16 * v;
      ob[(r * 32 + cc) * 32] = sgv * sig[u][v] * sm.xs[r][cc];
    }
  }
}

extern "C" void kernel_launch(void* const* d_in, const int* in_sizes, int n_in,
                              void* d_out, int out_size, void* d_ws, size_t ws_size,
                              hipStream_t stream) {
  const float* x      = (const float*)d_in[0];
  const float* pos_y  = (const float*)d_in[1];
  const float* wqvk_y = (const float*)d_in[2];
  const float* w0_y   = (const float*)d_in[3];
  const float* g_y    = (const float*)d_in[4];
  const float* b_y    = (const float*)d_in[5];
  const float* wqvk_x = (const float*)d_in[6];
  const float* w0_x   = (const float*)d_in[7];
  const float* g_x    = (const float*)d_in[8];
  const float* b_x    = (const float*)d_in[9];
  bf16*  gates = (bf16*)d_ws;                              // 1.5 MB
  float* wcbuf = (float*)((char*)d_ws + 1572864);          // 6*96*32 f32 = 72 KB

  hipLaunchKernelGGL(wc_kernel, dim3(6), dim3(256), 0, stream,
                     pos_y, wqvk_y, wqvk_x, wcbuf);
  hipLaunchKernelGGL(phase1_kernel, dim3(768), dim3(256), 0, stream,
                     x, pos_y, wcbuf, w0_x, g_x, b_x, gates);
  hipLaunchKernelGGL(phase2_kernel, dim3(24576), dim3(256), 0, stream,
                     x, pos_y, wcbuf, w0_y, g_y, b_y, gates, (float*)d_out);
}

// Round 3
// 446.141 us; speedup vs baseline: 1.0397x; 1.0124x over previous
//
#include <hip/hip_runtime.h>
#include <hip/hip_bf16.h>

// channel_Encoding_Block — f32, packed v_pk_fma_f32 core, 4 blocks/CU.
//
//  x[b,c,t,d,i] (i fastest). emb[b,c,i,t,j] = sum_d x[b,c,t,d,i]*pos[c,j,d].
//  out[b,c,t,j,i] = sig(ys_c[b,i,t]) * sig(ln_y[b,c,i,t,j]) * x[b,c,t,j,i].
//
//  Algebraic fold: qkv = x @ Wc^T with Wc = W @ pos^T (wc_kernel, once).
//  Score scale folded into Wc q-rows; log2e folded into g,b.
//
//  R3: LDS-pipe-bound (2400 cy/wave) -> cut bytes moved:
//   * E+qkv FUSED, one x-read feeds both (thread (u=tid>>5, j=tid&31):
//     E rows 4u..4u+3 col j; qkv tokens 4u..4u+3 x f in {j,j+32,j+64}).
//     wcF stride 36 -> all-b128. 1056 -> 768 cy.
//   * residual routed via esT scratch; W0 DEFERRED into dead Wc rows 0..31.
//   * attn re-tiled: lane (h=tid>>5, tg2=(tid>>2)&7, sg2=tid&3) computes
//     4t x 8s scores; K/V bytes/lane 512->128; den & PV partials reduced
//     across sg2 quad with DPP adds (VALU pipe). 780 -> ~290 cy.
//   * LN reduction via DPP quad_perm + row_ror (no ds_bpermute).
//
//  Phase1: 768 blocks (b,c) -> sig(ys) gates (bf16) into d_ws.
//  Phase2: 24576 blocks (b,c,i), XCD-swizzled.

using bf16 = __hip_bfloat16;
typedef float v2f __attribute__((ext_vector_type(2)));

__device__ __forceinline__ v2f pk_fma(v2f acc, v2f a, v2f b) {
  asm("v_pk_fma_f32 %0, %1, %2, %0" : "+v"(acc) : "v"(a), "v"(b));
  return acc;
}

// x += dpp_perm(x): VALU-pipe cross-lane add. 0xB1=quad xor1, 0x4E=quad xor2,
// 0x124=row_ror:4, 0x128=row_ror:8 (rows of 16 lanes).
template <int CTRL>
__device__ __forceinline__ float dpp_add(float x) {
  return x + __int_as_float(
      __builtin_amdgcn_mov_dpp(__float_as_int(x), CTRL, 0xF, 0xF, true));
}

struct __align__(16) SMem {
  float psJ[32][36];   // pos[j][d] (stage1); aoF[t][f] (stage2->3)
  float wcF[96][36];   // Wc [f][d] (stage1); rows 0..31 = w0[j][f] (stage2->3)
  float xs[32][32];    // x[t][d]
  float qS[32][36];    // q[t][4h+dh]; col32/33 = g*log2e / b*log2e
  float kT[32][36];    // k[4h+dh][s]; col32 = gate[t] (phase2)
  float vT[32][36];    // v[4h+dh][s]
  float esT[32][34];   // es^T: esT[j][t]
};                     // 40704 B -> 4 blocks/CU (<= 40960)

// ---------------------------------------------------------------- wc kernel
__global__ __launch_bounds__(256) void wc_kernel(
    const float* __restrict__ pos_y, const float* __restrict__ wqvk_y,
    const float* __restrict__ wqvk_x, float* __restrict__ wc)
{
  const int n = blockIdx.x;          // 0..5:  n<3 -> y-set (c=n), n>=3 -> x-set
  const int c = n % 3, xset = n / 3;
  const float* W = (xset ? wqvk_x : wqvk_y) + c * 3072;   // [96][32]
  const float* P = pos_y + (xset ? 2 : c) * 1024;         // [32][32]
  __shared__ float Ws[96][33];
  __shared__ float Ps[32][33];
  const int tid = threadIdx.x;
#pragma unroll
  for (int k = 0; k < 12; ++k) {
    const int e = tid * 12 + k;
    Ws[e >> 5][e & 31] = W[e];
  }
#pragma unroll
  for (int k = 0; k < 4; ++k) {
    const int e = tid * 4 + k;
    Ps[e >> 5][e & 31] = P[e];
  }
  __syncthreads();
  const int fg = tid >> 3, d0 = (tid & 7) * 4;
#pragma unroll
  for (int m = 0; m < 3; ++m) {
    const int f = fg + 32 * m;
    float s0 = 0.f, s1 = 0.f, s2 = 0.f, s3 = 0.f;
#pragma unroll
    for (int j = 0; j < 32; ++j) {
      const float w = Ws[f][j];
      s0 += w * Ps[j][d0];     s1 += w * Ps[j][d0 + 1];
      s2 += w * Ps[j][d0 + 2]; s3 += w * Ps[j][d0 + 3];
    }
    // q-rows (f%24 in [0,8)) carry the score scale 0.5*log2(e)
    const float sc = ((f % 24) < 8) ? 0.72134752f : 1.0f;
    float* o = wc + (size_t)n * 3072 + f * 32 + d0;
    o[0] = s0 * sc; o[1] = s1 * sc; o[2] = s2 * sc; o[3] = s3 * sc;
  }
}

// -------------------------------------------------------------- table load
__device__ __forceinline__ void load_tables(
    SMem& sm, int tid, const float* __restrict__ xbc, int i,
    const float* __restrict__ pos, const float* __restrict__ wcg,
    const float* __restrict__ g, const float* __restrict__ b)
{
  const int t = tid >> 3, dq = (tid & 7) * 4;
  // x slice: 4 strided scalars -> one float4 store
  float xv0 = xbc[(t * 32 + dq + 0) * 32 + i];
  float xv1 = xbc[(t * 32 + dq + 1) * 32 + i];
  float xv2 = xbc[(t * 32 + dq + 2) * 32 + i];
  float xv3 = xbc[(t * 32 + dq + 3) * 32 + i];
  *(float4*)&sm.xs[t][dq] = make_float4(xv0, xv1, xv2, xv3);
  // pos natural copy, float4
  {
    const int e = tid * 4;
    float4 p = *(const float4*)&pos[e];
    *(float4*)&sm.psJ[e >> 5][e & 31] = p;
  }
  // Wc natural copy [f][d] into stride-36 rows: 3 float4 loads -> 6 v2f stores
  {
    float wf[12];
    *(float4*)&wf[0] = *(const float4*)&wcg[tid * 12];
    *(float4*)&wf[4] = *(const float4*)&wcg[tid * 12 + 4];
    *(float4*)&wf[8] = *(const float4*)&wcg[tid * 12 + 8];
#pragma unroll
    for (int k = 0; k < 6; ++k) {
      const int e = tid * 12 + 2 * k;
      *(v2f*)&sm.wcF[e >> 5][e & 31] = v2f{wf[2 * k], wf[2 * k + 1]};
    }
  }
  if (tid < 32) {
    sm.qS[tid][32] = g[tid] * 1.44269504f;   // g * log2(e)
    sm.qS[tid][33] = b[tid] * 1.44269504f;   // b * log2(e)
  }
}

// sigmoid(LayerNorm(E + MHSA(E))): thread's 2x2 outputs at rows {g,g+16},
// cols {l,l+16} (g=tid>>4, l=tid&15).
__device__ __forceinline__ void mhsa_core(SMem& sm, int tid,
                                          const float* __restrict__ w0g,
                                          float sig_out[2][2])
{
  // ---- stage 1: FUSED E + qkv (x read once) ----
  {
    const int u = tid >> 5, j = tid & 31;
    const int tR = 4 * u;
    float* sp[3]; int st[3];
#pragma unroll
    for (int m = 0; m < 3; ++m) {
      const int f = j + 32 * m;
      const int dh = f / 24, r2 = f - 24 * dh;
      const int sel = r2 >> 3, cc = (r2 & 7) * 4 + dh;
      if (sel == 0)      { sp[m] = &sm.qS[0][0] + cc;      st[m] = 36; }
      else if (sel == 1) { sp[m] = &sm.kT[0][0] + cc * 36; st[m] = 1;  }
      else               { sp[m] = &sm.vT[0][0] + cc * 36; st[m] = 1;  }
    }
    v2f ea[4], acc[3][4];
#pragma unroll
    for (int k = 0; k < 4; ++k) ea[k] = v2f{0.f, 0.f};
#pragma unroll
    for (int m = 0; m < 3; ++m)
#pragma unroll
      for (int k = 0; k < 4; ++k) acc[m][k] = v2f{0.f, 0.f};
#pragma unroll
    for (int d4 = 0; d4 < 8; ++d4) {
      float4 x0 = *(const float4*)&sm.xs[tR + 0][4 * d4];   // 2-addr broadcast
      float4 x1 = *(const float4*)&sm.xs[tR + 1][4 * d4];
      float4 x2 = *(const float4*)&sm.xs[tR + 2][4 * d4];
      float4 x3 = *(const float4*)&sm.xs[tR + 3][4 * d4];
      float4 pj = *(const float4*)&sm.psJ[j][4 * d4];       // 9j banks: free
      float4 wa = *(const float4*)&sm.wcF[j][4 * d4];       // 9j banks: free
      float4 wb = *(const float4*)&sm.wcF[j + 32][4 * d4];
      float4 wc4 = *(const float4*)&sm.wcF[j + 64][4 * d4];
      v2f pl{pj.x, pj.y}, ph{pj.z, pj.w};
      v2f xl[4] = {v2f{x0.x,x0.y}, v2f{x1.x,x1.y}, v2f{x2.x,x2.y}, v2f{x3.x,x3.y}};
      v2f xh[4] = {v2f{x0.z,x0.w}, v2f{x1.z,x1.w}, v2f{x2.z,x2.w}, v2f{x3.z,x3.w}};
      v2f wl[3] = {v2f{wa.x,wa.y}, v2f{wb.x,wb.y}, v2f{wc4.x,wc4.y}};
      v2f wh[3] = {v2f{wa.z,wa.w}, v2f{wb.z,wb.w}, v2f{wc4.z,wc4.w}};
#pragma unroll
      for (int k = 0; k < 4; ++k) {
        ea[k] = pk_fma(ea[k], xl[k], pl);
        ea[k] = pk_fma(ea[k], xh[k], ph);
#pragma unroll
        for (int m = 0; m < 3; ++m) {
          acc[m][k] = pk_fma(acc[m][k], xl[k], wl[m]);
          acc[m][k] = pk_fma(acc[m][k], xh[k], wh[m]);
        }
      }
    }
    // residual hand-off: es^T[j][t]  (2 x b64, banks 2j+u: free)
    {
      const float e0 = ea[0][0] + ea[0][1], e1 = ea[1][0] + ea[1][1];
      const float e2 = ea[2][0] + ea[2][1], e3 = ea[3][0] + ea[3][1];
      *(v2f*)&sm.esT[j][tR]     = v2f{e0, e1};
      *(v2f*)&sm.esT[j][tR + 2] = v2f{e2, e3};
    }
    // qkv scatter: k/v rows token-contiguous b128; q rows scalar
#pragma unroll
    for (int m = 0; m < 3; ++m) {
      const float r0 = acc[m][0][0] + acc[m][0][1];
      const float r1 = acc[m][1][0] + acc[m][1][1];
      const float r2v = acc[m][2][0] + acc[m][2][1];
      const float r3 = acc[m][3][0] + acc[m][3][1];
      if (st[m] == 1) {
        *(float4*)(sp[m] + tR) = make_float4(r0, r1, r2v, r3);
      } else {
        sp[m][(tR + 0) * 36] = r0;
        sp[m][(tR + 1) * 36] = r1;
        sp[m][(tR + 2) * 36] = r2v;
        sp[m][(tR + 3) * 36] = r3;
      }
    }
  }
  // deferred W0 load (HBM latency overlaps the barrier + attention)
  float4 w0v = *(const float4*)&w0g[tid * 4];
  __syncthreads();
  // W0 into dead Wc rows 0..31 (read after next barrier)
  {
    const int e = tid * 4;
    *(float4*)&sm.wcF[e >> 5][e & 31] = w0v;
  }

  // ---- stage 2: attention, 4t x 8s per lane; quad-DPP reductions ----
  {
    const int h = tid >> 5, tg2 = (tid >> 2) & 7, sg2 = tid & 3;
    const int ta = 4 * tg2, s0 = 8 * sg2;
    float4 qr0 = *(const float4*)&sm.qS[ta + 0][4 * h];
    float4 qr1 = *(const float4*)&sm.qS[ta + 1][4 * h];
    float4 qr2 = *(const float4*)&sm.qS[ta + 2][4 * h];
    float4 qr3 = *(const float4*)&sm.qS[ta + 3][4 * h];
    const float qa_[4][4] = {
        {qr0.x, qr0.y, qr0.z, qr0.w},
        {qr1.x, qr1.y, qr1.z, qr1.w},
        {qr2.x, qr2.y, qr2.z, qr2.w},
        {qr3.x, qr3.y, qr3.z, qr3.w}};
    v2f sc[4][4];
#pragma unroll
    for (int kk = 0; kk < 4; ++kk)
#pragma unroll
      for (int sp2 = 0; sp2 < 4; ++sp2) sc[kk][sp2] = v2f{0.f, 0.f};
#pragma unroll
    for (int dh = 0; dh < 4; ++dh) {
      const float* kr = &sm.kT[4 * h + dh][s0];
      float4 ka = *(const float4*)&kr[0];
      float4 kb = *(const float4*)&kr[4];
      v2f k0{ka.x, ka.y}, k1{ka.z, ka.w}, k2{kb.x, kb.y}, k3{kb.z, kb.w};
#pragma unroll
      for (int kk = 0; kk < 4; ++kk) {
        v2f qv{qa_[kk][dh], qa_[kk][dh]};
        sc[kk][0] = pk_fma(sc[kk][0], qv, k0);
        sc[kk][1] = pk_fma(sc[kk][1], qv, k1);
        sc[kk][2] = pk_fma(sc[kk][2], qv, k2);
        sc[kk][3] = pk_fma(sc[kk][3], qv, k3);
      }
    }
    // exp + denominator (per-lane 8s partial, then quad reduce on VALU)
    float inv[4];
#pragma unroll
    for (int kk = 0; kk < 4; ++kk) {
#pragma unroll
      for (int sp2 = 0; sp2 < 4; ++sp2) {
        sc[kk][sp2][0] = exp2f(sc[kk][sp2][0]);
        sc[kk][sp2][1] = exp2f(sc[kk][sp2][1]);
      }
      v2f dv = sc[kk][0] + sc[kk][1];
      v2f dw = sc[kk][2] + sc[kk][3];
      dv += dw;
      float dn = dv[0] + dv[1];
      dn = dpp_add<0xB1>(dn);
      dn = dpp_add<0x4E>(dn);
      inv[kk] = __fdividef(1.0f, dn);
    }
    // PV partials over own 8s, quad-DPP reduce, lane sg2==0 stores b128 rows
    v2f pv[4][4];
#pragma unroll
    for (int kk = 0; kk < 4; ++kk)
#pragma unroll
      for (int dh = 0; dh < 4; ++dh) pv[kk][dh] = v2f{0.f, 0.f};
#pragma unroll
    for (int dh = 0; dh < 4; ++dh) {
      const float* vr = &sm.vT[4 * h + dh][s0];
      float4 va = *(const float4*)&vr[0];
      float4 vb = *(const float4*)&vr[4];
      v2f v0{va.x, va.y}, v1{va.z, va.w}, v2v{vb.x, vb.y}, v3{vb.z, vb.w};
#pragma unroll
      for (int kk = 0; kk < 4; ++kk) {
        pv[kk][dh] = pk_fma(pv[kk][dh], sc[kk][0], v0);
        pv[kk][dh] = pk_fma(pv[kk][dh], sc[kk][1], v1);
        pv[kk][dh] = pk_fma(pv[kk][dh], sc[kk][2], v2v);
        pv[kk][dh] = pk_fma(pv[kk][dh], sc[kk][3], v3);
      }
    }
    float ov[4][4];
#pragma unroll
    for (int kk = 0; kk < 4; ++kk)
#pragma unroll
      for (int dh = 0; dh < 4; ++dh) {
        float o = pv[kk][dh][0] + pv[kk][dh][1];
        o = dpp_add<0xB1>(o);
        o = dpp_add<0x4E>(o);
        ov[kk][dh] = o;
      }
    if (sg2 == 0) {
#pragma unroll
      for (int kk = 0; kk < 4; ++kk) {
        *(float4*)&sm.psJ[ta + kk][4 * h] = make_float4(
            ov[kk][0] * inv[kk], ov[kk][1] * inv[kk],
            ov[kk][2] * inv[kk], ov[kk][3] * inv[kk]);
      }
    }
  }
  __syncthreads();

  // ---- stage 3: proj + residual + LN (DPP) + sigmoid, 2x2 tile ----
  {
    const int g = tid >> 4, l = tid & 15;
    v2f a00{0.f,0.f}, a01{0.f,0.f}, a10{0.f,0.f}, a11{0.f,0.f};
#pragma unroll
    for (int f4 = 0; f4 < 8; ++f4) {
      float4 u0 = *(const float4*)&sm.psJ[g][4 * f4];        // aoF, broadcast
      float4 u1 = *(const float4*)&sm.psJ[g + 16][4 * f4];
      float4 w0 = *(const float4*)&sm.wcF[l][4 * f4];        // w0[j][f]
      float4 w1 = *(const float4*)&sm.wcF[l + 16][4 * f4];
      a00 = pk_fma(a00, v2f{u0.x, u0.y}, v2f{w0.x, w0.y});
      a00 = pk_fma(a00, v2f{u0.z, u0.w}, v2f{w0.z, w0.w});
      a01 = pk_fma(a01, v2f{u0.x, u0.y}, v2f{w1.x, w1.y});
      a01 = pk_fma(a01, v2f{u0.z, u0.w}, v2f{w1.z, w1.w});
      a10 = pk_fma(a10, v2f{u1.x, u1.y}, v2f{w0.x, w0.y});
      a10 = pk_fma(a10, v2f{u1.z, u1.w}, v2f{w0.z, w0.w});
      a11 = pk_fma(a11, v2f{u1.x, u1.y}, v2f{w1.x, w1.y});
      a11 = pk_fma(a11, v2f{u1.z, u1.w}, v2f{w1.z, w1.w});
    }
    float rr[2][2];
    rr[0][0] = a00[0] + a00[1] + sm.esT[l][g];
    rr[0][1] = a01[0] + a01[1] + sm.esT[l + 16][g];
    rr[1][0] = a10[0] + a10[1] + sm.esT[l][g + 16];
    rr[1][1] = a11[0] + a11[1] + sm.esT[l + 16][g + 16];
    float s1a = rr[0][0] + rr[0][1], s1b = rr[1][0] + rr[1][1];
    float s2a = rr[0][0]*rr[0][0] + rr[0][1]*rr[0][1];
    float s2b = rr[1][0]*rr[1][0] + rr[1][1]*rr[1][1];
    // 16-lane reduce on VALU: quad xor1, xor2, then row_ror 4, 8
    s1a = dpp_add<0xB1>(s1a); s1a = dpp_add<0x4E>(s1a);
    s1a = dpp_add<0x124>(s1a); s1a = dpp_add<0x128>(s1a);
    s2a = dpp_add<0xB1>(s2a); s2a = dpp_add<0x4E>(s2a);
    s2a = dpp_add<0x124>(s2a); s2a = dpp_add<0x128>(s2a);
    s1b = dpp_add<0xB1>(s1b); s1b = dpp_add<0x4E>(s1b);
    s1b = dpp_add<0x124>(s1b); s1b = dpp_add<0x128>(s1b);
    s2b = dpp_add<0xB1>(s2b); s2b = dpp_add<0x4E>(s2b);
    s2b = dpp_add<0x124>(s2b); s2b = dpp_add<0x128>(s2b);
    const float mua = s1a * (1.0f / 32.0f), mub = s1b * (1.0f / 32.0f);
    const float ra = rsqrtf(s2a * (1.0f / 32.0f) - mua * mua + 1e-5f);
    const float rb = rsqrtf(s2b * (1.0f / 32.0f) - mub * mub + 1e-5f);
    const float g0 = sm.qS[l][32],      b0 = sm.qS[l][33];   // pre-scaled log2e
    const float g1 = sm.qS[l + 16][32], b1 = sm.qS[l + 16][33];
    sig_out[0][0] = __fdividef(1.0f, 1.0f + exp2f(-((rr[0][0] - mua) * ra * g0 + b0)));
    sig_out[0][1] = __fdividef(1.0f, 1.0f + exp2f(-((rr[0][1] - mua) * ra * g1 + b1)));
    sig_out[1][0] = __fdividef(1.0f, 1.0f + exp2f(-((rr[1][0] - mub) * rb * g0 + b0)));
    sig_out[1][1] = __fdividef(1.0f, 1.0f + exp2f(-((rr[1][1] - mub) * rb * g1 + b1)));
  }
}

__global__ __launch_bounds__(256, 4) void phase1_kernel(
    const float* __restrict__ x, const float* __restrict__ pos_y,
    const float* __restrict__ wc, const float* __restrict__ w0_x,
    const float* __restrict__ g_x, const float* __restrict__ b_x,
    bf16* __restrict__ gates)
{
  __shared__ SMem sm;
  const int tid = threadIdx.x;
  const int n = blockIdx.x;          // 768 = 256*3
  const int c = n % 3, b = n / 3;
  const float* xbc = x + (size_t)(b * 3 + 2) * 32768;   // channel 2
  load_tables(sm, tid, xbc, 31, pos_y + 2 * 1024,
              wc + (size_t)(3 + c) * 3072, g_x, b_x);
  __syncthreads();
  float sig[2][2];
  mhsa_core(sm, tid, w0_x + c * 1024, sig);
  const int g = tid >> 4, l = tid & 15;
#pragma unroll
  for (int u = 0; u < 2; ++u)
#pragma unroll
    for (int v = 0; v < 2; ++v)
      gates[((c * 256 + b) * 32 + g + 16 * u) * 32 + l + 16 * v] =
          __float2bfloat16(sig[u][v]);
}

__global__ __launch_bounds__(256, 4) void phase2_kernel(
    const float* __restrict__ x, const float* __restrict__ pos_y,
    const float* __restrict__ wc, const float* __restrict__ w0_y,
    const float* __restrict__ g_y, const float* __restrict__ b_y,
    const bf16* __restrict__ gates, float* __restrict__ out)
{
  __shared__ SMem sm;
  const int tid = threadIdx.x;
  const int n = blockIdx.x;                    // 24576
  const int p = (n & 7) * 3072 + (n >> 3);     // XCD swizzle
  const int i = p & 31, bc = p >> 5;
  const int c = bc % 3, b = bc / 3;
  const float* xbc = x + (size_t)bc * 32768;
  load_tables(sm, tid, xbc, i, pos_y + c * 1024,
              wc + (size_t)c * 3072, g_y, b_y);
  if (tid < 32)
    sm.kT[tid][32] = __bfloat162float(gates[((c * 256 + b) * 32 + i) * 32 + tid]);
  __syncthreads();
  float sig[2][2];
  mhsa_core(sm, tid, w0_y + c * 1024, sig);
  const int g = tid >> 4, l = tid & 15;
  float* ob = out + (size_t)bc * 32768 + i;
#pragma unroll
  for (int u = 0; u < 2; ++u) {
    const int r = g + 16 * u;
    const float sgv = sm.kT[r][32];            // sig(ys_c[b, i, t])
#pragma unroll
    for (int v = 0; v < 2; ++v) {
      const int cc = l + 16 * v;
      ob[(r * 32 + cc) * 32] = sgv * sig[u][v] * sm.xs[r][cc];
    }
  }
}

extern "C" void kernel_launch(void* const* d_in, const int* in_sizes, int n_in,
                              void* d_out, int out_size, void* d_ws, size_t ws_size,
                              hipStream_t stream) {
  const float* x      = (const float*)d_in[0];
  const float* pos_y  = (const float*)d_in[1];
  const float* wqvk_y = (const float*)d_in[2];
  const float* w0_y   = (const float*)d_in[3];
  const float* g_y    = (const float*)d_in[4];
  const float* b_y    = (const float*)d_in[5];
  const float* wqvk_x = (const float*)d_in[6];
  const float* w0_x   = (const float*)d_in[7];
  const float* g_x    = (const float*)d_in[8];
  const float* b_x    = (const float*)d_in[9];
  bf16*  gates = (bf16*)d_ws;                              // 1.5 MB
  float* wcbuf = (float*)((char*)d_ws + 1572864);          // 6*96*32 f32 = 72 KB

  hipLaunchKernelGGL(wc_kernel, dim3(6), dim3(256), 0, stream,
                     pos_y, wqvk_y, wqvk_x, wcbuf);
  hipLaunchKernelGGL(phase1_kernel, dim3(768), dim3(256), 0, stream,
                     x, pos_y, wcbuf, w0_x, g_x, b_x, gates);
  hipLaunchKernelGGL(phase2_kernel, dim3(24576), dim3(256), 0, stream,
                     x, pos_y, wcbuf, w0_y, g_y, b_y, gates, (float*)d_out);
}

// Round 4
// 400.768 us; speedup vs baseline: 1.1574x; 1.1132x over previous
//
#include <hip/hip_runtime.h>
#include <hip/hip_bf16.h>

// channel_Encoding_Block — split-bf16 MFMA stage-A + f32 VALU attn/proj. 4 blocks/CU.
//
//  x[b,c,t,d,i] (i fastest). emb[b,c,i,t,j] = sum_d x[b,c,t,d,i]*pos[c,j,d].
//  out[b,c,t,j,i] = sig(ys_c[b,i,t]) * sig(ln_y[b,c,i,t,j]) * x[b,c,t,j,i].
//
//  Algebraic fold: qkv = x @ Wc^T with Wc = W @ pos^T. wc_kernel builds a
//  row-PERMUTED combined B = [k(32) | v(32) | q(32, pre-scaled) | pos(32)]
//  as SPLIT bf16 (hi+lo) so stage A runs on the matrix pipe:
//    D = aH*bH + aH*bL + aL*bH   (3 MFMAs, ~f32 accuracy, rel err ~2^-16)
//  Wave w: token-tile mt=w>>1; (w&1)==0 -> k/v tiles (b128 scatter),
//  (w&1)==1 -> q tiles (scalar scatter) + E tiles (regs across barrier).
//  E/aoF/w0 overlay the dead weight buffer after barrier 1.
//
//  Phase1: 768 blocks (b,c) -> sig(ys) gates (bf16) into d_ws.
//  Phase2: 24576 blocks (b,c,i), XCD-swizzled.

using bf16 = __hip_bfloat16;
typedef float v2f __attribute__((ext_vector_type(2)));
using short8 = __attribute__((ext_vector_type(8))) short;   // 8 bf16 (4 VGPRs)
using f32x4  = __attribute__((ext_vector_type(4))) float;

__device__ __forceinline__ v2f pk_fma(v2f acc, v2f a, v2f b) {
  asm("v_pk_fma_f32 %0, %1, %2, %0" : "+v"(acc) : "v"(a), "v"(b));
  return acc;
}

// x += dpp_perm(x): VALU-pipe cross-lane add. 0xB1=quad xor1, 0x4E=quad xor2,
// 0x124=row_ror:4, 0x128=row_ror:8 (rows of 16 lanes).
template <int CTRL>
__device__ __forceinline__ float dpp_add(float x) {
  return x + __int_as_float(
      __builtin_amdgcn_mov_dpp(__float_as_int(x), CTRL, 0xF, 0xF, true));
}

__device__ __forceinline__ ushort bf16_rne(float f) {
  uint u = __float_as_uint(f);
  return (ushort)((u + 0x7FFFu + ((u >> 16) & 1u)) >> 16);
}
__device__ __forceinline__ void split2(float x, ushort& h, ushort& l) {
  h = bf16_rne(x);
  l = bf16_rne(x - __uint_as_float((uint)h << 16));
}

struct __align__(16) SMem {
  ushort xsH[32][40];    // 2560: x hi-bf16 [t][d] (stride 40us = 80B, b128-ok)
  ushort xsL[32][40];    // 2560: x lo-bf16
  union {
    struct { ushort WH[128][40]; ushort WL[128][40]; } w;  // 20480 (stage A)
    struct {                                              // after barrier 1
      float esT[32][40];   // 5120: E^T [j][t]
      float aoF[32][36];   // 4608: attn out [t][f]
      float w0s[32][36];   // 4608: w0 [j][f]
    } s;
  } u;
  float qS[32][36];      // 4608: q[t][4h+dh]; col32/33 = g*log2e / b*log2e
  float kT[32][36];      // 4608: k[4h+dh][s]; col32 = gate[t] (phase2)
  float vT[32][36];      // 4608: v[4h+dh][s]
};                       // 39424 B -> 4 blocks/CU

// ------------------------------------------------- wc kernel (runs once)
// Builds per-set packed image: [hi 128x32][lo 128x32] ushorts (16384 B/set).
// Row order n: 0..31 k (cc=n), 32..63 v, 64..95 q (scaled), 96..127 pos.
__global__ __launch_bounds__(256) void wc_kernel(
    const float* __restrict__ pos_y, const float* __restrict__ wqvk_y,
    const float* __restrict__ wqvk_x, ushort* __restrict__ wc2)
{
  const int n6 = blockIdx.x;         // 0..5: n6<3 -> y-set (c=n6), else x-set
  const int c = n6 % 3, xset = n6 / 3;
  const float* W = (xset ? wqvk_x : wqvk_y) + c * 3072;   // [96][32] (f,j)
  const float* P = pos_y + (xset ? 2 : c) * 1024;         // [32][32] (j,d)
  __shared__ float Ws[96][33];
  __shared__ float Ps[32][33];
  const int tid = threadIdx.x;
#pragma unroll
  for (int k = 0; k < 12; ++k) {
    const int e = tid * 12 + k;
    Ws[e >> 5][e & 31] = W[e];
  }
#pragma unroll
  for (int k = 0; k < 4; ++k) {
    const int e = tid * 4 + k;
    Ps[e >> 5][e & 31] = P[e];
  }
  __syncthreads();
  const int n = tid & 127, half = tid >> 7;   // row n, d-range 16*half..+16
  float src[16];
  if (n >= 96) {
    const int j = n - 96;
#pragma unroll
    for (int dd = 0; dd < 16; ++dd) src[dd] = Ps[j][16 * half + dd];
  } else {
    const int sidx = n >> 5;          // 0=k,1=v,2=q
    const int m = n & 31, dh = m & 3, h = m >> 2;
    const int f = dh * 24 + (sidx == 0 ? 8 : (sidx == 1 ? 16 : 0)) + h;
    const float sc = (sidx == 2) ? 0.72134752f : 1.0f;  // 0.5*log2(e) on q
#pragma unroll
    for (int dd = 0; dd < 16; ++dd) {
      float s = 0.f;
      for (int j = 0; j < 32; ++j) s += Ws[f][j] * Ps[j][16 * half + dd];
      src[dd] = s * sc;
    }
  }
  ushort* base = wc2 + (size_t)n6 * 8192;
#pragma unroll
  for (int dd = 0; dd < 16; ++dd) {
    ushort h, l;
    split2(src[dd], h, l);
    base[n * 32 + 16 * half + dd]        = h;
    base[4096 + n * 32 + 16 * half + dd] = l;
  }
}

// -------------------------------------------------------------- table load
__device__ __forceinline__ void load_tables(
    SMem& sm, int tid, const float* __restrict__ xbc, int i,
    const ushort* __restrict__ wc2,
    const float* __restrict__ g, const float* __restrict__ b)
{
  const int t = tid >> 3, dq = (tid & 7) * 4;
  // x slice: 4 strided scalars -> split bf16 -> two short4 stores
  float xv[4];
#pragma unroll
  for (int k = 0; k < 4; ++k) xv[k] = xbc[(t * 32 + dq + k) * 32 + i];
  ushort hs[4], ls[4];
#pragma unroll
  for (int k = 0; k < 4; ++k) split2(xv[k], hs[k], ls[k]);
  *(short4*)&sm.xsH[t][dq] = make_short4((short)hs[0], (short)hs[1],
                                         (short)hs[2], (short)hs[3]);
  *(short4*)&sm.xsL[t][dq] = make_short4((short)ls[0], (short)ls[1],
                                         (short)ls[2], (short)ls[3]);
  // W image copy: thread copies one 64B row (0..127 -> WH, 128..255 -> WL)
  {
    const float4* src = (const float4*)(wc2 + tid * 32);
    float4 r0 = src[0], r1 = src[1], r2 = src[2], r3 = src[3];
    ushort* dst = (tid < 128) ? &sm.u.w.WH[tid][0] : &sm.u.w.WL[tid - 128][0];
    ((float4*)dst)[0] = r0; ((float4*)dst)[1] = r1;
    ((float4*)dst)[2] = r2; ((float4*)dst)[3] = r3;
  }
  if (tid < 32) {
    sm.qS[tid][32] = g[tid] * 1.44269504f;   // g * log2(e)
    sm.qS[tid][33] = b[tid] * 1.44269504f;   // b * log2(e)
  }
}

// sigmoid(LayerNorm(E + MHSA(E))): thread's 2x2 outputs at rows {g,g+16},
// cols {l,l+16} (g=tid>>4, l=tid&15).
__device__ __forceinline__ void mhsa_core(SMem& sm, int tid,
                                          const float* __restrict__ w0g,
                                          float sig_out[2][2])
{
  const int wv = tid >> 6, lane = tid & 63;
  const int lr = lane & 15, lk = lane >> 4;
  const int mt = wv >> 1;             // wave's token tile (0,1)
  const int qe = wv & 1;              // 0: k/v tiles; 1: q/E tiles
  const int t0 = mt * 16 + lk * 4;    // C rows (4 consecutive tokens)
  f32x4 eC0 = {0.f,0.f,0.f,0.f}, eC1 = {0.f,0.f,0.f,0.f};

  // ---- stage A: E+qkv on the matrix pipe (split-bf16, 3 MFMA/tile) ----
  {
    short8 aH = *(const short8*)&sm.xsH[mt * 16 + lr][lk * 8];
    short8 aL = *(const short8*)&sm.xsL[mt * 16 + lr][lk * 8];
    f32x4 acc[4];
#pragma unroll
    for (int q = 0; q < 4; ++q) {
      const int n = qe * 64 + q * 16 + lr;
      short8 bH = *(const short8*)&sm.u.w.WH[n][lk * 8];
      short8 bL = *(const short8*)&sm.u.w.WL[n][lk * 8];
      f32x4 c = {0.f, 0.f, 0.f, 0.f};
      c = __builtin_amdgcn_mfma_f32_16x16x32_bf16(aH, bH, c, 0, 0, 0);
      c = __builtin_amdgcn_mfma_f32_16x16x32_bf16(aH, bL, c, 0, 0, 0);
      c = __builtin_amdgcn_mfma_f32_16x16x32_bf16(aL, bH, c, 0, 0, 0);
      acc[q] = c;
    }
    if (qe == 0) {            // k rows (n 0..31 = cc), v rows (32..63)
      *(f32x4*)&sm.kT[lr][t0]      = acc[0];
      *(f32x4*)&sm.kT[lr + 16][t0] = acc[1];
      *(f32x4*)&sm.vT[lr][t0]      = acc[2];
      *(f32x4*)&sm.vT[lr + 16][t0] = acc[3];
    } else {                  // q rows (64..95 -> cc), E (96..127 -> regs)
#pragma unroll
      for (int r = 0; r < 4; ++r) {
        sm.qS[t0 + r][lr]      = acc[0][r];
        sm.qS[t0 + r][lr + 16] = acc[1][r];
      }
      eC0 = acc[2]; eC1 = acc[3];
    }
  }
  // deferred W0 load (HBM latency overlaps barrier + stores)
  float4 w0v = *(const float4*)&w0g[tid * 4];
  __syncthreads();
  // weight buffer dead -> overlay: E^T, then w0
  if (qe == 1) {
    *(f32x4*)&sm.u.s.esT[lr][t0]      = eC0;   // esT[j][t..t+3]
    *(f32x4*)&sm.u.s.esT[lr + 16][t0] = eC1;
  }
  { const int e = tid * 4; *(float4*)&sm.u.s.w0s[e >> 5][e & 31] = w0v; }

  // ---- stage 2: attention, 4t x 8s per lane; quad-DPP reductions ----
  {
    const int h = tid >> 5, tg2 = (tid >> 2) & 7, sg2 = tid & 3;
    const int ta = 4 * tg2, s0 = 8 * sg2;
    float4 qr0 = *(const float4*)&sm.qS[ta + 0][4 * h];
    float4 qr1 = *(const float4*)&sm.qS[ta + 1][4 * h];
    float4 qr2 = *(const float4*)&sm.qS[ta + 2][4 * h];
    float4 qr3 = *(const float4*)&sm.qS[ta + 3][4 * h];
    const float qa_[4][4] = {
        {qr0.x, qr0.y, qr0.z, qr0.w},
        {qr1.x, qr1.y, qr1.z, qr1.w},
        {qr2.x, qr2.y, qr2.z, qr2.w},
        {qr3.x, qr3.y, qr3.z, qr3.w}};
    v2f sc[4][4];
#pragma unroll
    for (int kk = 0; kk < 4; ++kk)
#pragma unroll
      for (int sp2 = 0; sp2 < 4; ++sp2) sc[kk][sp2] = v2f{0.f, 0.f};
#pragma unroll
    for (int dh = 0; dh < 4; ++dh) {
      const float* kr = &sm.kT[4 * h + dh][s0];
      float4 ka = *(const float4*)&kr[0];
      float4 kb = *(const float4*)&kr[4];
      v2f k0{ka.x, ka.y}, k1{ka.z, ka.w}, k2{kb.x, kb.y}, k3{kb.z, kb.w};
#pragma unroll
      for (int kk = 0; kk < 4; ++kk) {
        v2f qv{qa_[kk][dh], qa_[kk][dh]};
        sc[kk][0] = pk_fma(sc[kk][0], qv, k0);
        sc[kk][1] = pk_fma(sc[kk][1], qv, k1);
        sc[kk][2] = pk_fma(sc[kk][2], qv, k2);
        sc[kk][3] = pk_fma(sc[kk][3], qv, k3);
      }
    }
    float inv[4];
#pragma unroll
    for (int kk = 0; kk < 4; ++kk) {
#pragma unroll
      for (int sp2 = 0; sp2 < 4; ++sp2) {
        sc[kk][sp2][0] = exp2f(sc[kk][sp2][0]);
        sc[kk][sp2][1] = exp2f(sc[kk][sp2][1]);
      }
      v2f dv = sc[kk][0] + sc[kk][1];
      v2f dw = sc[kk][2] + sc[kk][3];
      dv += dw;
      float dn = dv[0] + dv[1];
      dn = dpp_add<0xB1>(dn);
      dn = dpp_add<0x4E>(dn);
      inv[kk] = __fdividef(1.0f, dn);
    }
    v2f pv[4][4];
#pragma unroll
    for (int kk = 0; kk < 4; ++kk)
#pragma unroll
      for (int dh = 0; dh < 4; ++dh) pv[kk][dh] = v2f{0.f, 0.f};
#pragma unroll
    for (int dh = 0; dh < 4; ++dh) {
      const float* vr = &sm.vT[4 * h + dh][s0];
      float4 va = *(const float4*)&vr[0];
      float4 vb = *(const float4*)&vr[4];
      v2f v0{va.x, va.y}, v1{va.z, va.w}, v2v{vb.x, vb.y}, v3{vb.z, vb.w};
#pragma unroll
      for (int kk = 0; kk < 4; ++kk) {
        pv[kk][dh] = pk_fma(pv[kk][dh], sc[kk][0], v0);
        pv[kk][dh] = pk_fma(pv[kk][dh], sc[kk][1], v1);
        pv[kk][dh] = pk_fma(pv[kk][dh], sc[kk][2], v2v);
        pv[kk][dh] = pk_fma(pv[kk][dh], sc[kk][3], v3);
      }
    }
    float ov[4][4];
#pragma unroll
    for (int kk = 0; kk < 4; ++kk)
#pragma unroll
      for (int dh = 0; dh < 4; ++dh) {
        float o = pv[kk][dh][0] + pv[kk][dh][1];
        o = dpp_add<0xB1>(o);
        o = dpp_add<0x4E>(o);
        ov[kk][dh] = o;
      }
    if (sg2 == 0) {
#pragma unroll
      for (int kk = 0; kk < 4; ++kk) {
        *(float4*)&sm.u.s.aoF[ta + kk][4 * h] = make_float4(
            ov[kk][0] * inv[kk], ov[kk][1] * inv[kk],
            ov[kk][2] * inv[kk], ov[kk][3] * inv[kk]);
      }
    }
  }
  __syncthreads();

  // ---- stage 3: proj + residual + LN (DPP) + sigmoid, 2x2 tile ----
  {
    const int g = tid >> 4, l = tid & 15;
    v2f a00{0.f,0.f}, a01{0.f,0.f}, a10{0.f,0.f}, a11{0.f,0.f};
#pragma unroll
    for (int f4 = 0; f4 < 8; ++f4) {
      float4 u0 = *(const float4*)&sm.u.s.aoF[g][4 * f4];       // broadcast
      float4 u1 = *(const float4*)&sm.u.s.aoF[g + 16][4 * f4];
      float4 w0 = *(const float4*)&sm.u.s.w0s[l][4 * f4];       // w0[j][f]
      float4 w1 = *(const float4*)&sm.u.s.w0s[l + 16][4 * f4];
      a00 = pk_fma(a00, v2f{u0.x, u0.y}, v2f{w0.x, w0.y});
      a00 = pk_fma(a00, v2f{u0.z, u0.w}, v2f{w0.z, w0.w});
      a01 = pk_fma(a01, v2f{u0.x, u0.y}, v2f{w1.x, w1.y});
      a01 = pk_fma(a01, v2f{u0.z, u0.w}, v2f{w1.z, w1.w});
      a10 = pk_fma(a10, v2f{u1.x, u1.y}, v2f{w0.x, w0.y});
      a10 = pk_fma(a10, v2f{u1.z, u1.w}, v2f{w0.z, w0.w});
      a11 = pk_fma(a11, v2f{u1.x, u1.y}, v2f{w1.x, w1.y});
      a11 = pk_fma(a11, v2f{u1.z, u1.w}, v2f{w1.z, w1.w});
    }
    float rr[2][2];
    rr[0][0] = a00[0] + a00[1] + sm.u.s.esT[l][g];
    rr[0][1] = a01[0] + a01[1] + sm.u.s.esT[l + 16][g];
    rr[1][0] = a10[0] + a10[1] + sm.u.s.esT[l][g + 16];
    rr[1][1] = a11[0] + a11[1] + sm.u.s.esT[l + 16][g + 16];
    float s1a = rr[0][0] + rr[0][1], s1b = rr[1][0] + rr[1][1];
    float s2a = rr[0][0]*rr[0][0] + rr[0][1]*rr[0][1];
    float s2b = rr[1][0]*rr[1][0] + rr[1][1]*rr[1][1];
    s1a = dpp_add<0xB1>(s1a); s1a = dpp_add<0x4E>(s1a);
    s1a = dpp_add<0x124>(s1a); s1a = dpp_add<0x128>(s1a);
    s2a = dpp_add<0xB1>(s2a); s2a = dpp_add<0x4E>(s2a);
    s2a = dpp_add<0x124>(s2a); s2a = dpp_add<0x128>(s2a);
    s1b = dpp_add<0xB1>(s1b); s1b = dpp_add<0x4E>(s1b);
    s1b = dpp_add<0x124>(s1b); s1b = dpp_add<0x128>(s1b);
    s2b = dpp_add<0xB1>(s2b); s2b = dpp_add<0x4E>(s2b);
    s2b = dpp_add<0x124>(s2b); s2b = dpp_add<0x128>(s2b);
    const float mua = s1a * (1.0f / 32.0f), mub = s1b * (1.0f / 32.0f);
    const float ra = rsqrtf(s2a * (1.0f / 32.0f) - mua * mua + 1e-5f);
    const float rb = rsqrtf(s2b * (1.0f / 32.0f) - mub * mub + 1e-5f);
    const float g0 = sm.qS[l][32],      b0 = sm.qS[l][33];
    const float g1 = sm.qS[l + 16][32], b1 = sm.qS[l + 16][33];
    sig_out[0][0] = __fdividef(1.0f, 1.0f + exp2f(-((rr[0][0] - mua) * ra * g0 + b0)));
    sig_out[0][1] = __fdividef(1.0f, 1.0f + exp2f(-((rr[0][1] - mua) * ra * g1 + b1)));
    sig_out[1][0] = __fdividef(1.0f, 1.0f + exp2f(-((rr[1][0] - mub) * rb * g0 + b0)));
    sig_out[1][1] = __fdividef(1.0f, 1.0f + exp2f(-((rr[1][1] - mub) * rb * g1 + b1)));
  }
}

__global__ __launch_bounds__(256, 4) void phase1_kernel(
    const float* __restrict__ x, const ushort* __restrict__ wc2,
    const float* __restrict__ w0_x,
    const float* __restrict__ g_x, const float* __restrict__ b_x,
    bf16* __restrict__ gates)
{
  __shared__ SMem sm;
  const int tid = threadIdx.x;
  const int n = blockIdx.x;          // 768 = 256*3
  const int c = n % 3, b = n / 3;
  const float* xbc = x + (size_t)(b * 3 + 2) * 32768;   // channel 2
  load_tables(sm, tid, xbc, 31, wc2 + (size_t)(3 + c) * 8192, g_x, b_x);
  __syncthreads();
  float sig[2][2];
  mhsa_core(sm, tid, w0_x + c * 1024, sig);
  const int g = tid >> 4, l = tid & 15;
#pragma unroll
  for (int u = 0; u < 2; ++u)
#pragma unroll
    for (int v = 0; v < 2; ++v)
      gates[((c * 256 + b) * 32 + g + 16 * u) * 32 + l + 16 * v] =
          __float2bfloat16(sig[u][v]);
}

__global__ __launch_bounds__(256, 4) void phase2_kernel(
    const float* __restrict__ x, const ushort* __restrict__ wc2,
    const float* __restrict__ w0_y,
    const float* __restrict__ g_y, const float* __restrict__ b_y,
    const bf16* __restrict__ gates, float* __restrict__ out)
{
  __shared__ SMem sm;
  const int tid = threadIdx.x;
  const int n = blockIdx.x;                    // 24576
  const int p = (n & 7) * 3072 + (n >> 3);     // XCD swizzle
  const int i = p & 31, bc = p >> 5;
  const int c = bc % 3, b = bc / 3;
  const float* xbc = x + (size_t)bc * 32768;
  load_tables(sm, tid, xbc, i, wc2 + (size_t)c * 8192, g_y, b_y);
  if (tid < 32)
    sm.kT[tid][32] = __bfloat162float(gates[((c * 256 + b) * 32 + i) * 32 + tid]);
  __syncthreads();
  float sig[2][2];
  mhsa_core(sm, tid, w0_y + c * 1024, sig);
  const int g = tid >> 4, l = tid & 15;
  float* ob = out + (size_t)bc * 32768 + i;
#pragma unroll
  for (int u = 0; u < 2; ++u) {
    const int r = g + 16 * u;
    const float sgv = sm.kT[r][32];            // sig(ys_c[b, i, t])
#pragma unroll
    for (int v = 0; v < 2; ++v) {
      const int cc = l + 16 * v;
      const float xv = __uint_as_float((uint)sm.xsH[r][cc] << 16) +
                       __uint_as_float((uint)sm.xsL[r][cc] << 16);
      ob[(r * 32 + cc) * 32] = sgv * sig[u][v] * xv;
    }
  }
}

extern "C" void kernel_launch(void* const* d_in, const int* in_sizes, int n_in,
                              void* d_out, int out_size, void* d_ws, size_t ws_size,
                              hipStream_t stream) {
  const float* x      = (const float*)d_in[0];
  const float* pos_y  = (const float*)d_in[1];
  const float* wqvk_y = (const float*)d_in[2];
  const float* w0_y   = (const float*)d_in[3];
  const float* g_y    = (const float*)d_in[4];
  const float* b_y    = (const float*)d_in[5];
  const float* wqvk_x = (const float*)d_in[6];
  const float* w0_x   = (const float*)d_in[7];
  const float* g_x    = (const float*)d_in[8];
  const float* b_x    = (const float*)d_in[9];
  bf16*   gates = (bf16*)d_ws;                             // 1.5 MB
  ushort* wc2   = (ushort*)((char*)d_ws + 1572864);        // 6*16384 B

  hipLaunchKernelGGL(wc_kernel, dim3(6), dim3(256), 0, stream,
                     pos_y, wqvk_y, wqvk_x, wc2);
  hipLaunchKernelGGL(phase1_kernel, dim3(768), dim3(256), 0, stream,
                     x, wc2, w0_x, g_x, b_x, gates);
  hipLaunchKernelGGL(phase2_kernel, dim3(24576), dim3(256), 0, stream,
                     x, wc2, w0_y, g_y, b_y, gates, (float*)d_out);
}